// Round 3
// baseline (873.307 us; speedup 1.0000x reference)
//
#include <hip/hip_runtime.h>

// NaryDisEmbedding: out[b,f,0:128]  = counts2(x[b,f]) @ emb2   (base-2 digit histogram, 16 digits)
//                   out[b,f,128:256]= counts3(x[b,f]) @ emb3   (base-3 digit histogram, 16 digits)
// x in [0, 50000): base-2 -> popcount of low 16 bits; base-3 -> only digits 0..9 can be
// nonzero (3^10 = 59049 > 49999), digits 10..15 contribute +6 to count of digit 0.
//
// R2 post-mortem: nontemporal stores ran at ~2.6 TB/s while the harness's own
// fillBuffer hits 6.2 TB/s on the same output buffer with regular stores —
// `nt` bypasses L2 write coalescing. Plain stores here.

#define B_DIM 4096
#define F_DIM 200
#define ROWS  (B_DIM * F_DIM)   // 819200
#define OUT_C 256               // 2 * EMBED_DIM

typedef float f32x4 __attribute__((ext_vector_type(4)));

__global__ __launch_bounds__(256) void nary_embed_kernel(
    const int*   __restrict__ x,
    const float* __restrict__ emb2,
    const float* __restrict__ emb3,
    float*       __restrict__ out)
{
    const int lane = threadIdx.x & 63;
    const int wave = threadIdx.x >> 6;      // 0..3 (4 waves per block)
    const int c4   = lane * 4;              // this lane's channel quad [c4, c4+4)

    // Per-lane embedding quads, loaded once, live in registers for the whole kernel.
    // Lanes 0..31 (c4 < 128): base-2 half. Lanes 32..63: base-3 half.
    const bool is2 = (c4 < 128);
    f32x4 e0, e1, e2;
    if (is2) {
        e0 = *(const f32x4*)(emb2 + 0 * 128 + c4);
        e1 = *(const f32x4*)(emb2 + 1 * 128 + c4);
        e2 = (f32x4){0.f, 0.f, 0.f, 0.f};   // weight f2 multiplies zero for base-2 lanes
    } else {
        const int d = c4 - 128;
        e0 = *(const f32x4*)(emb3 + 0 * 128 + d);
        e1 = *(const f32x4*)(emb3 + 1 * 128 + d);
        e2 = *(const f32x4*)(emb3 + 2 * 128 + d);
    }

    // Grid-stride over rows; one wave handles one full 256-channel row (1 KB store).
    const int rowStride = gridDim.x * 4;
    for (int row = blockIdx.x * 4 + wave; row < ROWS; row += rowStride) {
        const int v = x[row];               // wave-uniform -> scalar load, K$-resident

        // base-2 digit counts (16 digits)
        const int pc = __popc(v);           // v < 2^16

        // base-3 digit counts: 10 real digits; digits 10..15 are zero -> fold into c0
        int n1 = 0, n2 = 0, t = v;
        #pragma unroll
        for (int i = 0; i < 10; ++i) {
            const int q = t / 3;            // magic-multiply, no HW divide
            const int r = t - q * 3;
            n1 += (r == 1);
            n2 += (r == 2);
            t = q;
        }

        // Branch-free per-lane count selection.
        const float f0 = is2 ? (float)(16 - pc) : (float)(16 - n1 - n2);
        const float f1 = is2 ? (float)pc        : (float)n1;
        const float f2 = (float)n2;          // e2 == 0 on base-2 lanes

        f32x4 o = f0 * e0 + f1 * e1 + f2 * e2;

        // Wave writes one contiguous 1 KB row through L2 (full-line eviction).
        *((f32x4*)(out + (size_t)row * OUT_C) + lane) = o;
    }
}

extern "C" void kernel_launch(void* const* d_in, const int* in_sizes, int n_in,
                              void* d_out, int out_size, void* d_ws, size_t ws_size,
                              hipStream_t stream) {
    const int*   x    = (const int*)  d_in[0];
    const float* emb2 = (const float*)d_in[1];
    const float* emb3 = (const float*)d_in[2];
    float*       out  = (float*)d_out;

    // 2048 blocks x 256 threads = 8192 waves; 819200 rows / (2048*4 rows per sweep)
    // = exactly 100 iterations per wave, no tail divergence. 8 blocks/CU.
    nary_embed_kernel<<<dim3(2048), dim3(256), 0, stream>>>(x, emb2, emb3, out);
}

// Round 4
// 840.778 us; speedup vs baseline: 1.0387x; 1.0387x over previous
//
#include <hip/hip_runtime.h>

// NaryDisEmbedding: out[b,f,0:128]  = counts2(x[b,f]) @ emb2   (base-2 digits, 16 of them)
//                   out[b,f,128:256]= counts3(x[b,f]) @ emb3   (base-3 digits, 16 of them)
// x < 50000: base-2 -> popcount; base-3 -> digits 0..9 only (3^10 = 59049), rest fold into c0.
//
// Algebra: sum_k c_k * e_k  ==  16*e0 + c1*(e1-e0) + c2*(e2-e0)   (since c0 = 16 - c1 - c2)
// so the per-row work is 8 FMAs against hoisted register-resident diffs.
//
// R3 post-mortem: dur_us includes ~670us of harness re-poison fills; kernel itself ~195us
// (~4.3 TB/s) vs ~135-150us write floor. This round: contiguous 100-row chunk per wave,
// s_load_dwordx4-batched x (4 rows per uniform load, prefetched), 8-FMA form -> more
// independent store chains per wave, fewer issue bubbles.

#define ROWS      819200          // 4096 * 200
#define OUT_C     256             // 2 * EMBED_DIM
#define ROWS_PER_WAVE 100         // 819200 / (2048 blocks * 4 waves)

typedef float f32x4 __attribute__((ext_vector_type(4)));

__device__ __forceinline__ void do_row(int v, bool is2,
                                       const f32x4& base_v, const f32x4& d1, const f32x4& d2,
                                       float* __restrict__ dst)
{
    const int pc = __popc(v);                 // base-2 ones count (v < 2^16)
    int n1 = 0, n2 = 0, t = v;                // base-3 digit counts, 10 real digits
    #pragma unroll
    for (int k = 0; k < 10; ++k) {
        const int q = t / 3;                  // magic-multiply (uniform -> SALU)
        const int r = t - q * 3;
        n1 += (r == 1);
        n2 += (r == 2);
        t = q;
    }
    const float f1 = (float)(is2 ? pc : n1);  // per-lane select of the c1 count
    const float f2 = (float)n2;               // d2 == 0 on base-2 lanes
    *(f32x4*)dst = base_v + f1 * d1 + f2 * d2;
}

__global__ __launch_bounds__(256) void nary_embed_kernel(
    const int*   __restrict__ x,
    const float* __restrict__ emb2,
    const float* __restrict__ emb3,
    float*       __restrict__ out)
{
    const int lane = threadIdx.x & 63;
    const int wave = threadIdx.x >> 6;           // 0..3
    const int c4   = lane * 4;                   // channel quad [c4, c4+4)

    // Hoisted per-lane embedding combination registers.
    const bool is2 = (c4 < 128);
    f32x4 e0, e1, d2;
    if (is2) {
        e0 = *(const f32x4*)(emb2 + 0 * 128 + c4);
        e1 = *(const f32x4*)(emb2 + 1 * 128 + c4);
        d2 = (f32x4){0.f, 0.f, 0.f, 0.f};
    } else {
        const int d = c4 - 128;
        e0 = *(const f32x4*)(emb3 + 0 * 128 + d);
        e1 = *(const f32x4*)(emb3 + 1 * 128 + d);
        d2 = *(const f32x4*)(emb3 + 2 * 128 + d) - e0;
    }
    const f32x4 base_v = 16.f * e0;
    const f32x4 d1     = e1 - e0;

    // Each wave owns a contiguous 100-row chunk: 100 KB of output, 400 B of x.
    const int wid = blockIdx.x * 4 + wave;       // 0..8191
    const int*  xp = x + wid * ROWS_PER_WAVE;    // 16B-aligned (400*wid % 16 == 0)
    float*      op = out + (size_t)wid * ROWS_PER_WAVE * OUT_C + c4;

    // 25 macro-iterations: one wave-uniform int4 (s_load_dwordx4) feeds 4 rows.
    int4 cur = *(const int4*)xp;
    #pragma unroll 5
    for (int i = 0; i < ROWS_PER_WAVE / 4; ++i) {
        int4 nxt;
        if (i + 1 < ROWS_PER_WAVE / 4) nxt = *(const int4*)(xp + (i + 1) * 4);
        float* o0 = op + (size_t)(i * 4) * OUT_C;
        do_row(cur.x, is2, base_v, d1, d2, o0 + 0 * OUT_C);
        do_row(cur.y, is2, base_v, d1, d2, o0 + 1 * OUT_C);
        do_row(cur.z, is2, base_v, d1, d2, o0 + 2 * OUT_C);
        do_row(cur.w, is2, base_v, d1, d2, o0 + 3 * OUT_C);
        cur = nxt;
    }
}

extern "C" void kernel_launch(void* const* d_in, const int* in_sizes, int n_in,
                              void* d_out, int out_size, void* d_ws, size_t ws_size,
                              hipStream_t stream) {
    const int*   x    = (const int*)  d_in[0];
    const float* emb2 = (const float*)d_in[1];
    const float* emb3 = (const float*)d_in[2];
    float*       out  = (float*)d_out;

    // 2048 blocks x 4 waves = 8192 waves; 819200 rows / 8192 = exactly 100 rows/wave.
    nary_embed_kernel<<<dim3(2048), dim3(256), 0, stream>>>(x, emb2, emb3, out);
}